// Round 11
// baseline (1945.200 us; speedup 1.0000x reference)
//
#include <hip/hip_runtime.h>
#include <hip/hip_bf16.h>

#define DFEAT 128
#define THETA 0.25f
#define SRC_MASK 0xFFFFF
#define DLOW_SH 20
#define SLOWF (1 << 30)
#define SCAP 6144

typedef __attribute__((ext_vector_type(8))) short short8;
typedef __attribute__((ext_vector_type(4))) float f32x4;
typedef __attribute__((ext_vector_type(2))) int i32x2;

__device__ inline unsigned short bf16_bits(float x) {
    __hip_bfloat16 h = __float2bfloat16(x);
    return *reinterpret_cast<unsigned short*>(&h);
}
__device__ inline unsigned pk_bf16(float x, float y) {
    return (unsigned)bf16_bits(x) | ((unsigned)bf16_bits(y) << 16);
}
__device__ inline void fma8(float* A, const uint4 x, float v) {
    A[0] = fmaf(v, __uint_as_float(x.x << 16),         A[0]);
    A[1] = fmaf(v, __uint_as_float(x.x & 0xffff0000u), A[1]);
    A[2] = fmaf(v, __uint_as_float(x.y << 16),         A[2]);
    A[3] = fmaf(v, __uint_as_float(x.y & 0xffff0000u), A[3]);
    A[4] = fmaf(v, __uint_as_float(x.z << 16),         A[4]);
    A[5] = fmaf(v, __uint_as_float(x.z & 0xffff0000u), A[5]);
    A[6] = fmaf(v, __uint_as_float(x.w << 16),         A[6]);
    A[7] = fmaf(v, __uint_as_float(x.w & 0xffff0000u), A[7]);
}

// ===========================================================================
// Merged: blocks [0,cvtB) convert input->bf16; blocks [cvtB,..) bucket
// histogram (bcnt/done zeroed by a 4 KB memset before this kernel).
// ===========================================================================
__global__ __launch_bounds__(512) void k_cvt_hist(
    const float* __restrict__ in, uint4* __restrict__ o, int n8, int cvtB,
    const int* __restrict__ edst, int* __restrict__ bcnt, int E)
{
    int t = threadIdx.x;
    if ((int)blockIdx.x < cvtB) {
        int i = blockIdx.x * 512 + t;
        if (i >= n8) return;
        float4 a = reinterpret_cast<const float4*>(in)[(size_t)i * 2];
        float4 b = reinterpret_cast<const float4*>(in)[(size_t)i * 2 + 1];
        uint4 r;
        r.x = pk_bf16(a.x, a.y);
        r.y = pk_bf16(a.z, a.w);
        r.z = pk_bf16(b.x, b.y);
        r.w = pk_bf16(b.z, b.w);
        o[i] = r;
    } else {
        __shared__ int h[512];
        h[t] = 0;
        __syncthreads();
        int e0 = (blockIdx.x - cvtB) * 4096;
        #pragma unroll
        for (int k = 0; k < 8; ++k) {
            int e = e0 + t + k * 512;
            if (e < E) atomicAdd(&h[edst[e] >> 8], 1);
        }
        __syncthreads();
        if (h[t]) atomicAdd(&bcnt[t], h[t]);
    }
}

// ===========================================================================
// Block 0: bucket scan -> bbase/tail, rowptr[N]=E, empty-bucket rowptr guard.
// Blocks 1..4: W' = (THETA*W + (1-THETA)*I)^T bf16 pre-swizzled.
// ===========================================================================
__global__ __launch_bounds__(512) void k_bscan_wprep(
    const int* __restrict__ bcnt, int* __restrict__ bbase,
    int* __restrict__ tail, int* __restrict__ rowptr,
    int NBUCK, int N, int E,
    const float* __restrict__ W, unsigned short* __restrict__ wp)
{
    if (blockIdx.x == 0) {
        __shared__ int buf[512];
        int t = threadIdx.x;
        buf[t] = (t < NBUCK) ? bcnt[t] : 0;
        __syncthreads();
        for (int off = 1; off < 512; off <<= 1) {
            int y = (t >= off) ? buf[t - off] : 0;
            __syncthreads();
            buf[t] += y;
            __syncthreads();
        }
        if (t < NBUCK) {
            int base = t ? buf[t - 1] : 0;
            bbase[t] = base;
            tail[t]  = base;
            if (bcnt[t] == 0) {            // empty bucket: no sorter will
                int node0 = t << 8;        // write rowptr -- do it here
                int nn = min(256, N - node0);
                for (int i = 0; i < nn; ++i) rowptr[node0 + i] = base;
            }
        }
        if (t == 0) { bbase[NBUCK] = E; rowptr[N] = E; }
    } else {
        int item = (blockIdx.x - 1) * 512 + threadIdx.x;
        if (item >= 16 * DFEAT) return;
        int kg = item >> 7;
        int n  = item & 127;
        unsigned pk4[4];
        #pragma unroll
        for (int jj = 0; jj < 4; ++jj) {
            int k0 = kg * 8 + jj * 2;
            float w0 = THETA * W[(size_t)k0 * DFEAT + n];
            float w1 = THETA * W[(size_t)(k0 + 1) * DFEAT + n];
            if (k0 == n)     w0 += 1.0f - THETA;
            if (k0 + 1 == n) w1 += 1.0f - THETA;
            pk4[jj] = pk_bf16(w0, w1);
        }
        uint4 v = make_uint4(pk4[0], pk4[1], pk4[2], pk4[3]);
        int slot = kg ^ (n & 7);
        *reinterpret_cast<uint4*>(&wp[n * DFEAT + slot * 8]) = v;
    }
}

// ===========================================================================
// Fused partition + sort.  Phase 1 = bucket partition (LDS staged, coalesced
// bucket-region writes).  Each block then release-fences and atomically adds
// its per-bucket contribution to done[]; the LAST contributor of a bucket
// immediately counting-sorts it (phase 2, LDS pool reused), writing rowptr.
// Device-scope fences per G16 make prior csr writes visible to the sorter.
// ===========================================================================
__global__ __launch_bounds__(512) void k_bpart_sort(
    const int* __restrict__ esrc, const int* __restrict__ edst,
    const float* __restrict__ eval_, int* __restrict__ tail,
    int2* __restrict__ csr, int E,
    const int* __restrict__ bcnt, int* __restrict__ done,
    const int* __restrict__ bbase, int* __restrict__ rowptr, int N)
{
    __shared__ char pool[52224];
    __shared__ int dlist[512];
    __shared__ int dnum;

    int* histB = (int*)pool;                                  // 512 ints
    int* offsB = (int*)(pool + 2048);                         // 512 ints
    int* gbase = (int*)(pool + 4096);                         // 512 ints
    unsigned short* bkOf = (unsigned short*)(pool + 6144);    // 4096 u16
    int2* stage = (int2*)(pool + 14336);                      // 4096 int2

    int t  = threadIdx.x;
    int e0 = blockIdx.x * 4096;
    int szb = min(4096, E - e0);

    histB[t] = 0;
    if (t == 0) dnum = 0;
    __syncthreads();

    int myb[8], myr[8];
    int2 mye[8];
    #pragma unroll
    for (int k = 0; k < 8; ++k) {
        int e = e0 + t + k * 512;
        myb[k] = -1;
        if (e < E) {
            int d = edst[e];
            int b = d >> 8;
            mye[k] = make_int2(esrc[e] | ((d & 255) << DLOW_SH),
                               __float_as_int(eval_[e]));
            myb[k] = b;
            myr[k] = atomicAdd(&histB[b], 1);
        }
    }
    __syncthreads();

    offsB[t] = histB[t];
    __syncthreads();
    for (int off = 1; off < 512; off <<= 1) {
        int y = (t >= off) ? offsB[t - off] : 0;
        __syncthreads();
        offsB[t] += y;
        __syncthreads();
    }
    if (histB[t] > 0) gbase[t] = atomicAdd(&tail[t], histB[t]);
    __syncthreads();

    #pragma unroll
    for (int k = 0; k < 8; ++k) {
        if (myb[k] >= 0) {
            int exb = myb[k] ? offsB[myb[k] - 1] : 0;
            int x = exb + myr[k];
            stage[x] = mye[k];
            bkOf[x]  = (unsigned short)myb[k];
        }
    }
    __syncthreads();

    for (int j = t; j < szb; j += 512) {
        int b   = bkOf[j];
        int exb = b ? offsB[b - 1] : 0;
        csr[gbase[b] + (j - exb)] = stage[j];
    }
    __syncthreads();
    __threadfence();                       // release: our csr writes visible

    if (histB[t] > 0) {
        int c   = histB[t];
        int old = atomicAdd(&done[t], c);
        if (old + c == bcnt[t]) {          // we are the last contributor
            int slot = atomicAdd(&dnum, 1);
            dlist[slot] = t;
        }
    }
    __syncthreads();
    const int nd = dnum;
    if (nd == 0) return;

    // ---- phase 2: sort each completed bucket (LDS pool reused)
    int*  cntN  = (int*)pool;                                 // 256 ints
    int*  offsN = (int*)(pool + 1024);                        // 256 ints
    int*  curN  = (int*)(pool + 2048);                        // 256 ints
    int2* st2   = (int2*)(pool + 3072);                       // SCAP int2

    for (int di = 0; di < nd; ++di) {
        int b = dlist[di];
        __syncthreads();                   // prev iteration's LDS fully read
        __threadfence();                   // acquire: other blocks' csr writes
        int lo = bbase[b], hi = bbase[b + 1];
        int sz = hi - lo;
        int node0 = b << 8;

        if (sz > SCAP) {                   // impossible on uniform data
            if (t < 256) {
                int n = node0 + t;
                if (n < N) rowptr[n] = lo | SLOWF;
            }
            continue;
        }

        if (t < 256) cntN[t] = 0;
        for (int j = t; j < sz; j += 512) st2[j] = csr[lo + j];
        __syncthreads();
        for (int j = t; j < sz; j += 512)
            atomicAdd(&cntN[(st2[j].x >> DLOW_SH) & 255], 1);
        __syncthreads();

        if (t < 256) offsN[t] = cntN[t];
        __syncthreads();
        for (int off = 1; off < 256; off <<= 1) {
            int y = (t >= off && t < 256) ? offsN[t - off] : 0;
            __syncthreads();
            if (t < 256) offsN[t] += y;
            __syncthreads();
        }
        if (t < 256) {
            int ex = t ? offsN[t - 1] : 0;
            curN[t] = ex;
            int n = node0 + t;
            if (n < N) rowptr[n] = lo + ex;
        }
        __syncthreads();

        for (int j = t; j < sz; j += 512) {
            int n = (st2[j].x >> DLOW_SH) & 255;
            int pos = atomicAdd(&curN[n], 1);
            csr[lo + pos] = st2[j];
        }
    }
}

// ===========================================================================
// Fused gather + MFMA (R8 config: 16-row tile, one node per 16-lane group,
// 8-deep batches) + h0 loads hoisted ahead of the edge walk.
// ===========================================================================
__global__ __launch_bounds__(256) void k_fused4(
    const unsigned short* __restrict__ in16, const int2* __restrict__ csr,
    const int* __restrict__ rowptr, const float* __restrict__ h0,
    const float* __restrict__ input, const unsigned short* __restrict__ wp,
    const float* __restrict__ alpha, float* __restrict__ out, int N)
{
    __shared__ unsigned short At[16 * DFEAT];      // 4 KB

    const int wv   = threadIdx.x >> 6;
    const int lane = threadIdx.x & 63;
    const int ng   = lane >> 4;
    const int s    = lane & 15;

    const int row0 = blockIdx.x * 16;
    const int r    = wv * 4 + ng;
    const int node = row0 + r;

    const float a   = 0.5f / (1.0f + __expf(-alpha[0]));
    const float oma = 1.0f - a;

    float A[8] = {0.f, 0.f, 0.f, 0.f, 0.f, 0.f, 0.f, 0.f};

    if (node < N) {
        int rp = rowptr[node];
        int beg, end;
        if (rp & SLOWF) {
            beg = rp & ~SLOWF;
            int nn = min((((node >> 8) + 1) << 8), N);
            end = rowptr[nn] & ~SLOWF;
        } else {
            beg = rp;
            end = rowptr[node + 1] & ~SLOWF;
        }
        const int dlow = node & 255;

        // h0 loads issued EARLY: latency hides under the edge walk
        size_t gb = (size_t)node * DFEAT + s * 8;
        f32x4 h0a = __builtin_nontemporal_load(
            reinterpret_cast<const f32x4*>(&h0[gb]));
        f32x4 h0b = __builtin_nontemporal_load(
            reinterpret_cast<const f32x4*>(&h0[gb + 4]));

        for (int e = beg; e < end; e += 8) {
            i32x2 p[8];
            uint4 x[8];
            float v[8];
            #pragma unroll
            for (int i = 0; i < 8; ++i) {
                int idx = (e + i < end) ? (e + i) : beg;   // clamp: always valid
                p[i] = __builtin_nontemporal_load(
                    reinterpret_cast<const i32x2*>(&csr[idx]));
            }
            #pragma unroll
            for (int i = 0; i < 8; ++i) {
                x[i] = *reinterpret_cast<const uint4*>(
                    &in16[(size_t)(p[i].x & SRC_MASK) * DFEAT + s * 8]);
                bool ok = (e + i < end) && (((p[i].x >> DLOW_SH) & 255) == dlow);
                v[i] = ok ? __int_as_float(p[i].y) : 0.f;
            }
            #pragma unroll
            for (int i = 0; i < 8; ++i) fma8(A, x[i], v[i]);
        }

        float b0 = oma * A[0] + a * h0a.x;
        float b1 = oma * A[1] + a * h0a.y;
        float b2 = oma * A[2] + a * h0a.z;
        float b3 = oma * A[3] + a * h0a.w;
        float b4 = oma * A[4] + a * h0b.x;
        float b5 = oma * A[5] + a * h0b.y;
        float b6 = oma * A[6] + a * h0b.z;
        float b7 = oma * A[7] + a * h0b.w;
        uint4 pk;
        pk.x = pk_bf16(b0, b1);
        pk.y = pk_bf16(b2, b3);
        pk.z = pk_bf16(b4, b5);
        pk.w = pk_bf16(b6, b7);
        *reinterpret_cast<uint4*>(&At[r * DFEAT + ((s ^ (r & 7)) << 3)]) = pk;
    }
    __syncthreads();

    // --- MFMA phase: wave wv computes cols [wv*32, wv*32+32)
    const int m  = lane & 15;
    const int kb = lane >> 4;
    const int n1 = wv * 32 + m;
    const int n2 = n1 + 16;

    short8 bw1[4], bw2[4];
    #pragma unroll
    for (int kk = 0; kk < 4; ++kk) {
        int w = kk * 4 + kb;
        bw1[kk] = *reinterpret_cast<const short8*>(
            &wp[n1 * DFEAT + ((w ^ (n1 & 7)) << 3)]);
        bw2[kk] = *reinterpret_cast<const short8*>(
            &wp[n2 * DFEAT + ((w ^ (n2 & 7)) << 3)]);
    }

    f32x4 acc0 = {0.f, 0.f, 0.f, 0.f};
    f32x4 acc1 = {0.f, 0.f, 0.f, 0.f};
    #pragma unroll
    for (int kk = 0; kk < 4; ++kk) {
        short8 af = *reinterpret_cast<const short8*>(
            &At[m * DFEAT + (((kk * 4 + kb) ^ (m & 7)) << 3)]);
        acc0 = __builtin_amdgcn_mfma_f32_16x16x32_bf16(af, bw1[kk], acc0, 0, 0, 0);
        acc1 = __builtin_amdgcn_mfma_f32_16x16x32_bf16(af, bw2[kk], acc1, 0, 0, 0);
    }

    #pragma unroll
    for (int q = 0; q < 4; ++q) {
        int row = row0 + kb * 4 + q;
        if (row < N) {
            size_t gi = (size_t)row * DFEAT + n1;
            float r0 = __builtin_nontemporal_load(&input[gi]);
            float r1 = __builtin_nontemporal_load(&input[gi + 16]);
            __builtin_nontemporal_store(acc0[q] + r0, &out[gi]);
            __builtin_nontemporal_store(acc1[q] + r1, &out[gi + 16]);
        }
    }
}

// ===========================================================================
// Plan B/C fallbacks (unchanged)
// ===========================================================================
__global__ void k_hist(const int* __restrict__ edst, int* __restrict__ cnt, int E) {
    int i = blockIdx.x * blockDim.x + threadIdx.x;
    int e4 = i * 4;
    if (e4 + 4 <= E) {
        int4 d = *reinterpret_cast<const int4*>(&edst[e4]);
        atomicAdd(&cnt[d.x], 1);
        atomicAdd(&cnt[d.y], 1);
        atomicAdd(&cnt[d.z], 1);
        atomicAdd(&cnt[d.w], 1);
    } else {
        for (int e = e4; e < E; ++e) atomicAdd(&cnt[edst[e]], 1);
    }
}

__global__ void k_scanA(const int* __restrict__ cnt, int* __restrict__ part, int N) {
    __shared__ int s[256];
    int i = blockIdx.x * 256 + threadIdx.x;
    s[threadIdx.x] = (i < N) ? cnt[i] : 0;
    __syncthreads();
    for (int off = 128; off > 0; off >>= 1) {
        if (threadIdx.x < off) s[threadIdx.x] += s[threadIdx.x + off];
        __syncthreads();
    }
    if (threadIdx.x == 0) part[blockIdx.x] = s[0];
}

__global__ void k_scanB(int* __restrict__ part, int* __restrict__ rowptr, int B, int N) {
    __shared__ int buf[1024];
    int t = threadIdx.x;
    buf[t] = (t < B) ? part[t] : 0;
    __syncthreads();
    for (int off = 1; off < 1024; off <<= 1) {
        int y = (t >= off) ? buf[t - off] : 0;
        __syncthreads();
        buf[t] += y;
        __syncthreads();
    }
    if (t < B) part[t] = (t == 0) ? 0 : buf[t - 1];
    if (t == B - 1) rowptr[N] = buf[t];
}

__global__ void k_scanC(const int* __restrict__ cnt, const int* __restrict__ part,
                        int* __restrict__ rowptr, int N) {
    __shared__ int buf[256];
    int t = threadIdx.x;
    int i = blockIdx.x * 256 + t;
    buf[t] = (i < N) ? cnt[i] : 0;
    __syncthreads();
    for (int off = 1; off < 256; off <<= 1) {
        int y = (t >= off) ? buf[t - off] : 0;
        __syncthreads();
        buf[t] += y;
        __syncthreads();
    }
    if (i < N) rowptr[i] = part[blockIdx.x] + ((t == 0) ? 0 : buf[t - 1]);
}

__global__ void k_slot(const int* __restrict__ esrc, const int* __restrict__ edst,
                       const float* __restrict__ eval_, const int* __restrict__ rowptr,
                       int* __restrict__ cnt, int2* __restrict__ csr, int E) {
    int i = blockIdx.x * blockDim.x + threadIdx.x;
    int e4 = i * 4;
    if (e4 + 4 <= E) {
        int4   s = *reinterpret_cast<const int4*>(&esrc[e4]);
        int4   d = *reinterpret_cast<const int4*>(&edst[e4]);
        float4 v = *reinterpret_cast<const float4*>(&eval_[e4]);
        int r;
        r = atomicSub(&cnt[d.x], 1); csr[rowptr[d.x] + r - 1] = make_int2(s.x, __float_as_int(v.x));
        r = atomicSub(&cnt[d.y], 1); csr[rowptr[d.y] + r - 1] = make_int2(s.y, __float_as_int(v.y));
        r = atomicSub(&cnt[d.z], 1); csr[rowptr[d.z] + r - 1] = make_int2(s.z, __float_as_int(v.z));
        r = atomicSub(&cnt[d.w], 1); csr[rowptr[d.w] + r - 1] = make_int2(s.w, __float_as_int(v.w));
    } else {
        for (int e = e4; e < E; ++e) {
            int d = edst[e];
            int r = atomicSub(&cnt[d], 1);
            csr[rowptr[d] + r - 1] = make_int2(esrc[e], __float_as_int(eval_[e]));
        }
    }
}

__global__ __launch_bounds__(256) void k_gather(
    const float* __restrict__ input, const int2* __restrict__ csr,
    const int* __restrict__ rowptr, const float* __restrict__ h0,
    const float* __restrict__ alpha, float* __restrict__ out, int N)
{
    int w    = (int)(((long long)blockIdx.x * blockDim.x + threadIdx.x) >> 6);
    int lane = threadIdx.x & 63;
    if (w >= N) return;
    int beg = rowptr[w], end = rowptr[w + 1];
    float ax = 0.f, ay = 0.f, bx = 0.f, by = 0.f;
    int i = beg;
    for (; i + 2 <= end; i += 2) {
        int2 p0 = csr[i], p1 = csr[i + 1];
        float2 x0 = *(const float2*)&input[(size_t)p0.x * DFEAT + lane * 2];
        float2 x1 = *(const float2*)&input[(size_t)p1.x * DFEAT + lane * 2];
        float v0 = __int_as_float(p0.y), v1 = __int_as_float(p1.y);
        ax = fmaf(v0, x0.x, ax); ay = fmaf(v0, x0.y, ay);
        bx = fmaf(v1, x1.x, bx); by = fmaf(v1, x1.y, by);
    }
    if (i < end) {
        int2 p = csr[i];
        float2 x = *(const float2*)&input[(size_t)p.x * DFEAT + lane * 2];
        float v = __int_as_float(p.y);
        ax = fmaf(v, x.x, ax); ay = fmaf(v, x.y, ay);
    }
    float hx = ax + bx, hy = ay + by;
    float a   = 0.5f / (1.0f + __expf(-alpha[0]));
    float oma = 1.0f - a;
    float2 h0v = *(const float2*)&h0[(size_t)w * DFEAT + lane * 2];
    float2 sv;
    sv.x = oma * hx + a * h0v.x;
    sv.y = oma * hy + a * h0v.y;
    *(float2*)&out[(size_t)w * DFEAT + lane * 2] = sv;
}

__global__ __launch_bounds__(256) void gcn_scatter(
    const float* __restrict__ input, const int* __restrict__ esrc,
    const int* __restrict__ edst, const float* __restrict__ eval_,
    float* __restrict__ hi, int E)
{
    long long t = (long long)blockIdx.x * blockDim.x + threadIdx.x;
    int e = (int)(t >> 6);
    if (e >= E) return;
    int lane = (int)(t & 63);
    int s = esrc[e]; int d = edst[e]; float v = eval_[e];
    const float2 x = *reinterpret_cast<const float2*>(&input[(size_t)s * DFEAT + lane * 2]);
    float* p = &hi[(size_t)d * DFEAT + lane * 2];
    unsafeAtomicAdd(p,     x.x * v);
    unsafeAtomicAdd(p + 1, x.y * v);
}

template <bool BLEND>
__global__ __launch_bounds__(256) void gcn_epilogue(
    float* __restrict__ out, const float* __restrict__ h0,
    const float* __restrict__ inp, const float* __restrict__ W,
    const float* __restrict__ alpha, int N)
{
    __shared__ __hip_bfloat16 Wl[DFEAT * DFEAT];
    __shared__ float4 S4[16][DFEAT / 4];

    const float a   = 0.5f / (1.0f + __expf(-alpha[0]));
    const float oma = 1.0f - a;

    for (int i = threadIdx.x; i < DFEAT * DFEAT; i += 256) {
        int k = i >> 7, j = i & 127;
        float w = W[i] * THETA;
        if (k == j) w += 1.0f - THETA;
        Wl[i] = __float2bfloat16(w);
    }

    const int j  = threadIdx.x & 127;
    const int rg = threadIdx.x >> 7;

    for (int base = blockIdx.x * 16; base < N; base += gridDim.x * 16) {
        const int rows = min(16, N - base);
        __syncthreads();
        for (int i = threadIdx.x; i < rows * 32; i += 256) {
            int r = i >> 5, c = i & 31;
            size_t gph = (size_t)(base + r) * (DFEAT / 4) + c;
            float4 hv = reinterpret_cast<const float4*>(out)[gph];
            float4 sv;
            if (BLEND) {
                float4 h0v = reinterpret_cast<const float4*>(h0)[gph];
                sv.x = oma * hv.x + a * h0v.x;
                sv.y = oma * hv.y + a * h0v.y;
                sv.z = oma * hv.z + a * h0v.z;
                sv.w = oma * hv.w + a * h0v.w;
            } else {
                sv = hv;
            }
            S4[r][c] = sv;
        }
        __syncthreads();

        float acc[8];
        #pragma unroll
        for (int r = 0; r < 8; r++) acc[r] = 0.0f;
        for (int k = 0; k < DFEAT; k += 4) {
            float w0 = __bfloat162float(Wl[(k + 0) * DFEAT + j]);
            float w1 = __bfloat162float(Wl[(k + 1) * DFEAT + j]);
            float w2 = __bfloat162float(Wl[(k + 2) * DFEAT + j]);
            float w3 = __bfloat162float(Wl[(k + 3) * DFEAT + j]);
            #pragma unroll
            for (int r = 0; r < 8; r++) {
                float4 s4 = S4[rg * 8 + r][k >> 2];
                acc[r] = fmaf(s4.x, w0, acc[r]);
                acc[r] = fmaf(s4.y, w1, acc[r]);
                acc[r] = fmaf(s4.z, w2, acc[r]);
                acc[r] = fmaf(s4.w, w3, acc[r]);
            }
        }
        #pragma unroll
        for (int r = 0; r < 8; r++) {
            int rr = rg * 8 + r;
            if (rr < rows) {
                size_t gph = (size_t)(base + rr) * DFEAT + j;
                out[gph] = acc[r] + inp[gph];
            }
        }
    }
}

extern "C" void kernel_launch(void* const* d_in, const int* in_sizes, int n_in,
                              void* d_out, int out_size, void* d_ws, size_t ws_size,
                              hipStream_t stream) {
    const float* input = (const float*)d_in[0];
    const int*   esrc  = (const int*)  d_in[1];
    const int*   edst  = (const int*)  d_in[2];
    const float* eval_ = (const float*)d_in[3];
    const float* h0    = (const float*)d_in[4];
    const float* W     = (const float*)d_in[5];
    const float* alpha = (const float*)d_in[6];

    const int N = in_sizes[0] / DFEAT;
    const int E = in_sizes[1];
    float* out = (float*)d_out;
    const int B = (N + 255) / 256;

    // ---- Plan A layout (bytes):
    //   in16 | csr | rowptr[(N+1)] | bucket arrays (2080 ints) | wprep
    size_t bA_in16   = 0;
    size_t bA_csr    = (bA_in16 + (size_t)N * DFEAT * 2 + 15) & ~(size_t)15;
    size_t bA_rowptr = bA_csr + (size_t)E * 8;
    size_t bA_bkt    = bA_rowptr + (size_t)(N + 1) * 4;
    size_t bA_wp     = (bA_bkt + 2080 * 4 + 15) & ~(size_t)15;
    size_t needA     = bA_wp + (size_t)DFEAT * DFEAT * 2;

    // ---- Plan B layout (ints)
    size_t o_rowptr = 0;
    size_t o_cnt    = o_rowptr + (size_t)(N + 1);
    size_t o_part   = o_cnt + (size_t)N;
    size_t o_csr    = (o_part + 1024 + 1) & ~(size_t)1;
    size_t needB    = o_csr * 4 + (size_t)E * 8;

    const int NBUCK = (N + 255) >> 8;

    if (ws_size >= needA && N <= 131072 && N >= 1600) {
        unsigned short* in16 = (unsigned short*)((char*)d_ws + bA_in16);
        int2* csr    = (int2*)((char*)d_ws + bA_csr);
        int*  rowptr = (int*) ((char*)d_ws + bA_rowptr);
        int*  bcnt   = (int*) ((char*)d_ws + bA_bkt);          // [512]
        int*  done   = bcnt + 512;                              // [512]
        int*  bbase  = done + 512;                              // [513]
        int*  tail   = bbase + 513;                             // [512]
        unsigned short* wp = (unsigned short*)((char*)d_ws + bA_wp);

        int n8     = N * DFEAT / 8;
        int ntiles = (N + 15) / 16;
        int nEB    = (E + 4095) / 4096;
        int cvtB   = (n8 + 511) / 512;

        hipMemsetAsync(bcnt, 0, 1024 * sizeof(int), stream);   // bcnt + done
        k_cvt_hist<<<dim3(cvtB + nEB),   dim3(512), 0, stream>>>(input, (uint4*)in16,
                                                                 n8, cvtB, edst, bcnt, E);
        k_bscan_wprep<<<dim3(5),         dim3(512), 0, stream>>>(bcnt, bbase, tail,
                                                                 rowptr, NBUCK, N, E,
                                                                 W, wp);
        k_bpart_sort<<<dim3(nEB),        dim3(512), 0, stream>>>(esrc, edst, eval_,
                                                                 tail, csr, E,
                                                                 bcnt, done, bbase,
                                                                 rowptr, N);
        k_fused4<<<dim3(ntiles),         dim3(256), 0, stream>>>(in16, csr, rowptr,
                                                                 h0, input, wp, alpha,
                                                                 out, N);
    } else if (ws_size >= needB && B <= 1024) {
        int*  rowptr = (int*)d_ws + o_rowptr;
        int*  cnt    = (int*)d_ws + o_cnt;
        int*  part   = (int*)d_ws + o_part;
        int2* csr    = (int2*)((int*)d_ws + o_csr);
        int E4 = (E + 3) / 4;

        hipMemsetAsync(cnt, 0, (size_t)N * sizeof(int), stream);
        k_hist <<<dim3((E4 + 255) / 256), dim3(256), 0, stream>>>(edst, cnt, E);
        k_scanA<<<dim3(B),               dim3(256), 0, stream>>>(cnt, part, N);
        k_scanB<<<dim3(1),               dim3(1024), 0, stream>>>(part, rowptr, B, N);
        k_scanC<<<dim3(B),               dim3(256), 0, stream>>>(cnt, part, rowptr, N);
        k_slot <<<dim3((E4 + 255) / 256), dim3(256), 0, stream>>>(esrc, edst, eval_,
                                                                  rowptr, cnt, csr, E);
        k_gather<<<dim3((N + 3) / 4),    dim3(256), 0, stream>>>(input, csr, rowptr,
                                                                 h0, alpha, out, N);
        gcn_epilogue<false><<<dim3(2048), dim3(256), 0, stream>>>(out, h0, input, W,
                                                                  alpha, N);
    } else {
        hipMemsetAsync(out, 0, (size_t)N * DFEAT * sizeof(float), stream);
        long long threads = (long long)E * 64;
        unsigned  nblk    = (unsigned)((threads + 255) / 256);
        gcn_scatter<<<dim3(nblk), dim3(256), 0, stream>>>(input, esrc, edst, eval_, out, E);
        gcn_epilogue<true><<<dim3(2048), dim3(256), 0, stream>>>(out, h0, input, W,
                                                                 alpha, N);
    }
}

// Round 12
// 170.963 us; speedup vs baseline: 11.3779x; 11.3779x over previous
//
#include <hip/hip_runtime.h>
#include <hip/hip_bf16.h>

#define DFEAT 128
#define THETA 0.25f
#define SRC_MASK 0xFFFFF
#define DLOW_SH 20
#define SLOWF (1 << 30)
#define SCAP 6144

typedef __attribute__((ext_vector_type(8))) short short8;
typedef __attribute__((ext_vector_type(4))) float f32x4;
typedef __attribute__((ext_vector_type(2))) int i32x2;

__device__ inline unsigned short bf16_bits(float x) {
    __hip_bfloat16 h = __float2bfloat16(x);
    return *reinterpret_cast<unsigned short*>(&h);
}
__device__ inline unsigned pk_bf16(float x, float y) {
    return (unsigned)bf16_bits(x) | ((unsigned)bf16_bits(y) << 16);
}
__device__ inline void fma8(float* A, const uint4 x, float v) {
    A[0] = fmaf(v, __uint_as_float(x.x << 16),         A[0]);
    A[1] = fmaf(v, __uint_as_float(x.x & 0xffff0000u), A[1]);
    A[2] = fmaf(v, __uint_as_float(x.y << 16),         A[2]);
    A[3] = fmaf(v, __uint_as_float(x.y & 0xffff0000u), A[3]);
    A[4] = fmaf(v, __uint_as_float(x.z << 16),         A[4]);
    A[5] = fmaf(v, __uint_as_float(x.z & 0xffff0000u), A[5]);
    A[6] = fmaf(v, __uint_as_float(x.w << 16),         A[6]);
    A[7] = fmaf(v, __uint_as_float(x.w & 0xffff0000u), A[7]);
}

// ===========================================================================
// Merged: blocks [0,cvtB) convert input->bf16; blocks [cvtB,..) bucket
// histogram (bcnt zeroed by memset before this kernel).
// ===========================================================================
__global__ __launch_bounds__(512) void k_cvt_hist(
    const float* __restrict__ in, uint4* __restrict__ o, int n8, int cvtB,
    const int* __restrict__ edst, int* __restrict__ bcnt, int E)
{
    int t = threadIdx.x;
    if ((int)blockIdx.x < cvtB) {
        int i = blockIdx.x * 512 + t;
        if (i >= n8) return;
        float4 a = reinterpret_cast<const float4*>(in)[(size_t)i * 2];
        float4 b = reinterpret_cast<const float4*>(in)[(size_t)i * 2 + 1];
        uint4 r;
        r.x = pk_bf16(a.x, a.y);
        r.y = pk_bf16(a.z, a.w);
        r.z = pk_bf16(b.x, b.y);
        r.w = pk_bf16(b.z, b.w);
        o[i] = r;
    } else {
        __shared__ int h[512];
        h[t] = 0;
        __syncthreads();
        int e0 = (blockIdx.x - cvtB) * 4096;
        #pragma unroll
        for (int k = 0; k < 8; ++k) {
            int e = e0 + t + k * 512;
            if (e < E) atomicAdd(&h[edst[e] >> 8], 1);
        }
        __syncthreads();
        if (h[t]) atomicAdd(&bcnt[t], h[t]);
    }
}

// ===========================================================================
// Block 0: bucket scan -> bbase/tail, rowptr[N]=E, empty-bucket rowptr guard.
// Blocks 1..4: W' = (THETA*W + (1-THETA)*I)^T bf16 pre-swizzled.
// ===========================================================================
__global__ __launch_bounds__(512) void k_bscan_wprep(
    const int* __restrict__ bcnt, int* __restrict__ bbase,
    int* __restrict__ tail, int* __restrict__ rowptr,
    int NBUCK, int N, int E,
    const float* __restrict__ W, unsigned short* __restrict__ wp)
{
    if (blockIdx.x == 0) {
        __shared__ int buf[512];
        int t = threadIdx.x;
        buf[t] = (t < NBUCK) ? bcnt[t] : 0;
        __syncthreads();
        for (int off = 1; off < 512; off <<= 1) {
            int y = (t >= off) ? buf[t - off] : 0;
            __syncthreads();
            buf[t] += y;
            __syncthreads();
        }
        if (t < NBUCK) {
            int base = t ? buf[t - 1] : 0;
            bbase[t] = base;
            tail[t]  = base;
            if (bcnt[t] == 0) {            // empty bucket: no sorter will
                int node0 = t << 8;        // write rowptr -- do it here
                int nn = min(256, N - node0);
                for (int i = 0; i < nn; ++i) rowptr[node0 + i] = base;
            }
        }
        if (t == 0) { bbase[NBUCK] = E; rowptr[N] = E; }
    } else {
        int item = (blockIdx.x - 1) * 512 + threadIdx.x;
        if (item >= 16 * DFEAT) return;
        int kg = item >> 7;
        int n  = item & 127;
        unsigned pk4[4];
        #pragma unroll
        for (int jj = 0; jj < 4; ++jj) {
            int k0 = kg * 8 + jj * 2;
            float w0 = THETA * W[(size_t)k0 * DFEAT + n];
            float w1 = THETA * W[(size_t)(k0 + 1) * DFEAT + n];
            if (k0 == n)     w0 += 1.0f - THETA;
            if (k0 + 1 == n) w1 += 1.0f - THETA;
            pk4[jj] = pk_bf16(w0, w1);
        }
        uint4 v = make_uint4(pk4[0], pk4[1], pk4[2], pk4[3]);
        int slot = kg ^ (n & 7);
        *reinterpret_cast<uint4*>(&wp[n * DFEAT + slot * 8]) = v;
    }
}

// ===========================================================================
// Partition edges into bucket-grouped csr.  Entry word0 = src | (dst&255)<<20.
// ===========================================================================
__global__ __launch_bounds__(512) void k_bpart(
    const int* __restrict__ esrc, const int* __restrict__ edst,
    const float* __restrict__ eval_, int* __restrict__ tail,
    int2* __restrict__ csr, int E)
{
    __shared__ int histB[512];
    __shared__ int offsB[512];
    __shared__ int gbase[512];
    __shared__ unsigned short bkOf[4096];
    __shared__ int2 stage[4096];

    int t  = threadIdx.x;
    int e0 = blockIdx.x * 4096;
    int szb = min(4096, E - e0);

    histB[t] = 0;
    __syncthreads();

    int myb[8], myr[8];
    int2 mye[8];
    #pragma unroll
    for (int k = 0; k < 8; ++k) {
        int e = e0 + t + k * 512;
        myb[k] = -1;
        if (e < E) {
            int d = edst[e];
            int b = d >> 8;
            mye[k] = make_int2(esrc[e] | ((d & 255) << DLOW_SH),
                               __float_as_int(eval_[e]));
            myb[k] = b;
            myr[k] = atomicAdd(&histB[b], 1);
        }
    }
    __syncthreads();

    offsB[t] = histB[t];
    __syncthreads();
    for (int off = 1; off < 512; off <<= 1) {
        int y = (t >= off) ? offsB[t - off] : 0;
        __syncthreads();
        offsB[t] += y;
        __syncthreads();
    }
    if (histB[t] > 0) gbase[t] = atomicAdd(&tail[t], histB[t]);
    __syncthreads();

    #pragma unroll
    for (int k = 0; k < 8; ++k) {
        if (myb[k] >= 0) {
            int exb = myb[k] ? offsB[myb[k] - 1] : 0;
            int x = exb + myr[k];
            stage[x] = mye[k];
            bkOf[x]  = (unsigned short)myb[k];
        }
    }
    __syncthreads();

    for (int j = t; j < szb; j += 512) {
        int b   = bkOf[j];
        int exb = b ? offsB[b - 1] : 0;
        csr[gbase[b] + (j - exb)] = stage[j];
    }
}

// ===========================================================================
// Per-bucket counting sort by node; LDS read -> scatter-write to global
// (bucket window ~32 KB -> L2-local).  Writes rowptr.  SLOWF fallback.
// ===========================================================================
__global__ __launch_bounds__(512) void k_bsort(const int* __restrict__ bbase,
                                               int2* __restrict__ csr,
                                               int* __restrict__ rowptr, int N)
{
    __shared__ int2 stage[SCAP];
    __shared__ int cntN[256];
    __shared__ int offsN[256];
    __shared__ int curN[256];

    int b  = blockIdx.x;
    int lo = bbase[b], hi = bbase[b + 1];
    int sz = hi - lo;
    int t  = threadIdx.x;
    int node0 = b << 8;

    if (sz > SCAP) {
        if (t < 256) { int n = node0 + t; if (n < N) rowptr[n] = lo | SLOWF; }
        return;
    }

    if (t < 256) cntN[t] = 0;
    for (int j = t; j < sz; j += 512) stage[j] = csr[lo + j];
    __syncthreads();
    for (int j = t; j < sz; j += 512)
        atomicAdd(&cntN[(stage[j].x >> DLOW_SH) & 255], 1);
    __syncthreads();

    if (t < 256) offsN[t] = cntN[t];
    __syncthreads();
    for (int off = 1; off < 256; off <<= 1) {
        int y = (t >= off && t < 256) ? offsN[t - off] : 0;
        __syncthreads();
        if (t < 256) offsN[t] += y;
        __syncthreads();
    }
    if (t < 256) {
        int ex = t ? offsN[t - 1] : 0;
        curN[t] = ex;
        int n = node0 + t;
        if (n < N) rowptr[n] = lo + ex;
    }
    __syncthreads();

    for (int j = t; j < sz; j += 512) {
        int n = (stage[j].x >> DLOW_SH) & 255;
        int pos = atomicAdd(&curN[n], 1);
        csr[lo + pos] = stage[j];
    }
}

// ===========================================================================
// Fused gather + MFMA (best-measured R8 config: 16-row tile, one node per
// 16-lane group, 8-deep batches) + h0 loads hoisted ahead of the edge walk.
// ===========================================================================
__global__ __launch_bounds__(256) void k_fused4(
    const unsigned short* __restrict__ in16, const int2* __restrict__ csr,
    const int* __restrict__ rowptr, const float* __restrict__ h0,
    const float* __restrict__ input, const unsigned short* __restrict__ wp,
    const float* __restrict__ alpha, float* __restrict__ out, int N)
{
    __shared__ unsigned short At[16 * DFEAT];      // 4 KB

    const int wv   = threadIdx.x >> 6;
    const int lane = threadIdx.x & 63;
    const int ng   = lane >> 4;
    const int s    = lane & 15;

    const int row0 = blockIdx.x * 16;
    const int r    = wv * 4 + ng;
    const int node = row0 + r;

    const float a   = 0.5f / (1.0f + __expf(-alpha[0]));
    const float oma = 1.0f - a;

    float A[8] = {0.f, 0.f, 0.f, 0.f, 0.f, 0.f, 0.f, 0.f};

    if (node < N) {
        int rp = rowptr[node];
        int beg, end;
        if (rp & SLOWF) {
            beg = rp & ~SLOWF;
            int nn = min((((node >> 8) + 1) << 8), N);
            end = rowptr[nn] & ~SLOWF;
        } else {
            beg = rp;
            end = rowptr[node + 1] & ~SLOWF;
        }
        const int dlow = node & 255;

        // h0 loads issued EARLY: latency hides under the edge walk
        size_t gb = (size_t)node * DFEAT + s * 8;
        f32x4 h0a = __builtin_nontemporal_load(
            reinterpret_cast<const f32x4*>(&h0[gb]));
        f32x4 h0b = __builtin_nontemporal_load(
            reinterpret_cast<const f32x4*>(&h0[gb + 4]));

        for (int e = beg; e < end; e += 8) {
            i32x2 p[8];
            uint4 x[8];
            float v[8];
            #pragma unroll
            for (int i = 0; i < 8; ++i) {
                int idx = (e + i < end) ? (e + i) : beg;   // clamp: always valid
                p[i] = __builtin_nontemporal_load(
                    reinterpret_cast<const i32x2*>(&csr[idx]));
            }
            #pragma unroll
            for (int i = 0; i < 8; ++i) {
                x[i] = *reinterpret_cast<const uint4*>(
                    &in16[(size_t)(p[i].x & SRC_MASK) * DFEAT + s * 8]);
                bool ok = (e + i < end) && (((p[i].x >> DLOW_SH) & 255) == dlow);
                v[i] = ok ? __int_as_float(p[i].y) : 0.f;
            }
            #pragma unroll
            for (int i = 0; i < 8; ++i) fma8(A, x[i], v[i]);
        }

        float b0 = oma * A[0] + a * h0a.x;
        float b1 = oma * A[1] + a * h0a.y;
        float b2 = oma * A[2] + a * h0a.z;
        float b3 = oma * A[3] + a * h0a.w;
        float b4 = oma * A[4] + a * h0b.x;
        float b5 = oma * A[5] + a * h0b.y;
        float b6 = oma * A[6] + a * h0b.z;
        float b7 = oma * A[7] + a * h0b.w;
        uint4 pk;
        pk.x = pk_bf16(b0, b1);
        pk.y = pk_bf16(b2, b3);
        pk.z = pk_bf16(b4, b5);
        pk.w = pk_bf16(b6, b7);
        *reinterpret_cast<uint4*>(&At[r * DFEAT + ((s ^ (r & 7)) << 3)]) = pk;
    }
    __syncthreads();

    // --- MFMA phase: wave wv computes cols [wv*32, wv*32+32)
    const int m  = lane & 15;
    const int kb = lane >> 4;
    const int n1 = wv * 32 + m;
    const int n2 = n1 + 16;

    short8 bw1[4], bw2[4];
    #pragma unroll
    for (int kk = 0; kk < 4; ++kk) {
        int w = kk * 4 + kb;
        bw1[kk] = *reinterpret_cast<const short8*>(
            &wp[n1 * DFEAT + ((w ^ (n1 & 7)) << 3)]);
        bw2[kk] = *reinterpret_cast<const short8*>(
            &wp[n2 * DFEAT + ((w ^ (n2 & 7)) << 3)]);
    }

    f32x4 acc0 = {0.f, 0.f, 0.f, 0.f};
    f32x4 acc1 = {0.f, 0.f, 0.f, 0.f};
    #pragma unroll
    for (int kk = 0; kk < 4; ++kk) {
        short8 af = *reinterpret_cast<const short8*>(
            &At[m * DFEAT + (((kk * 4 + kb) ^ (m & 7)) << 3)]);
        acc0 = __builtin_amdgcn_mfma_f32_16x16x32_bf16(af, bw1[kk], acc0, 0, 0, 0);
        acc1 = __builtin_amdgcn_mfma_f32_16x16x32_bf16(af, bw2[kk], acc1, 0, 0, 0);
    }

    #pragma unroll
    for (int q = 0; q < 4; ++q) {
        int row = row0 + kb * 4 + q;
        if (row < N) {
            size_t gi = (size_t)row * DFEAT + n1;
            float r0 = __builtin_nontemporal_load(&input[gi]);
            float r1 = __builtin_nontemporal_load(&input[gi + 16]);
            __builtin_nontemporal_store(acc0[q] + r0, &out[gi]);
            __builtin_nontemporal_store(acc1[q] + r1, &out[gi + 16]);
        }
    }
}

// ===========================================================================
// Plan B/C fallbacks (unchanged)
// ===========================================================================
__global__ void k_hist(const int* __restrict__ edst, int* __restrict__ cnt, int E) {
    int i = blockIdx.x * blockDim.x + threadIdx.x;
    int e4 = i * 4;
    if (e4 + 4 <= E) {
        int4 d = *reinterpret_cast<const int4*>(&edst[e4]);
        atomicAdd(&cnt[d.x], 1);
        atomicAdd(&cnt[d.y], 1);
        atomicAdd(&cnt[d.z], 1);
        atomicAdd(&cnt[d.w], 1);
    } else {
        for (int e = e4; e < E; ++e) atomicAdd(&cnt[edst[e]], 1);
    }
}

__global__ void k_scanA(const int* __restrict__ cnt, int* __restrict__ part, int N) {
    __shared__ int s[256];
    int i = blockIdx.x * 256 + threadIdx.x;
    s[threadIdx.x] = (i < N) ? cnt[i] : 0;
    __syncthreads();
    for (int off = 128; off > 0; off >>= 1) {
        if (threadIdx.x < off) s[threadIdx.x] += s[threadIdx.x + off];
        __syncthreads();
    }
    if (threadIdx.x == 0) part[blockIdx.x] = s[0];
}

__global__ void k_scanB(int* __restrict__ part, int* __restrict__ rowptr, int B, int N) {
    __shared__ int buf[1024];
    int t = threadIdx.x;
    buf[t] = (t < B) ? part[t] : 0;
    __syncthreads();
    for (int off = 1; off < 1024; off <<= 1) {
        int y = (t >= off) ? buf[t - off] : 0;
        __syncthreads();
        buf[t] += y;
        __syncthreads();
    }
    if (t < B) part[t] = (t == 0) ? 0 : buf[t - 1];
    if (t == B - 1) rowptr[N] = buf[t];
}

__global__ void k_scanC(const int* __restrict__ cnt, const int* __restrict__ part,
                        int* __restrict__ rowptr, int N) {
    __shared__ int buf[256];
    int t = threadIdx.x;
    int i = blockIdx.x * 256 + t;
    buf[t] = (i < N) ? cnt[i] : 0;
    __syncthreads();
    for (int off = 1; off < 256; off <<= 1) {
        int y = (t >= off) ? buf[t - off] : 0;
        __syncthreads();
        buf[t] += y;
        __syncthreads();
    }
    if (i < N) rowptr[i] = part[blockIdx.x] + ((t == 0) ? 0 : buf[t - 1]);
}

__global__ void k_slot(const int* __restrict__ esrc, const int* __restrict__ edst,
                       const float* __restrict__ eval_, const int* __restrict__ rowptr,
                       int* __restrict__ cnt, int2* __restrict__ csr, int E) {
    int i = blockIdx.x * blockDim.x + threadIdx.x;
    int e4 = i * 4;
    if (e4 + 4 <= E) {
        int4   s = *reinterpret_cast<const int4*>(&esrc[e4]);
        int4   d = *reinterpret_cast<const int4*>(&edst[e4]);
        float4 v = *reinterpret_cast<const float4*>(&eval_[e4]);
        int r;
        r = atomicSub(&cnt[d.x], 1); csr[rowptr[d.x] + r - 1] = make_int2(s.x, __float_as_int(v.x));
        r = atomicSub(&cnt[d.y], 1); csr[rowptr[d.y] + r - 1] = make_int2(s.y, __float_as_int(v.y));
        r = atomicSub(&cnt[d.z], 1); csr[rowptr[d.z] + r - 1] = make_int2(s.z, __float_as_int(v.z));
        r = atomicSub(&cnt[d.w], 1); csr[rowptr[d.w] + r - 1] = make_int2(s.w, __float_as_int(v.w));
    } else {
        for (int e = e4; e < E; ++e) {
            int d = edst[e];
            int r = atomicSub(&cnt[d], 1);
            csr[rowptr[d] + r - 1] = make_int2(esrc[e], __float_as_int(eval_[e]));
        }
    }
}

__global__ __launch_bounds__(256) void k_gather(
    const float* __restrict__ input, const int2* __restrict__ csr,
    const int* __restrict__ rowptr, const float* __restrict__ h0,
    const float* __restrict__ alpha, float* __restrict__ out, int N)
{
    int w    = (int)(((long long)blockIdx.x * blockDim.x + threadIdx.x) >> 6);
    int lane = threadIdx.x & 63;
    if (w >= N) return;
    int beg = rowptr[w], end = rowptr[w + 1];
    float ax = 0.f, ay = 0.f, bx = 0.f, by = 0.f;
    int i = beg;
    for (; i + 2 <= end; i += 2) {
        int2 p0 = csr[i], p1 = csr[i + 1];
        float2 x0 = *(const float2*)&input[(size_t)p0.x * DFEAT + lane * 2];
        float2 x1 = *(const float2*)&input[(size_t)p1.x * DFEAT + lane * 2];
        float v0 = __int_as_float(p0.y), v1 = __int_as_float(p1.y);
        ax = fmaf(v0, x0.x, ax); ay = fmaf(v0, x0.y, ay);
        bx = fmaf(v1, x1.x, bx); by = fmaf(v1, x1.y, by);
    }
    if (i < end) {
        int2 p = csr[i];
        float2 x = *(const float2*)&input[(size_t)p.x * DFEAT + lane * 2];
        float v = __int_as_float(p.y);
        ax = fmaf(v, x.x, ax); ay = fmaf(v, x.y, ay);
    }
    float hx = ax + bx, hy = ay + by;
    float a   = 0.5f / (1.0f + __expf(-alpha[0]));
    float oma = 1.0f - a;
    float2 h0v = *(const float2*)&h0[(size_t)w * DFEAT + lane * 2];
    float2 sv;
    sv.x = oma * hx + a * h0v.x;
    sv.y = oma * hy + a * h0v.y;
    *(float2*)&out[(size_t)w * DFEAT + lane * 2] = sv;
}

__global__ __launch_bounds__(256) void gcn_scatter(
    const float* __restrict__ input, const int* __restrict__ esrc,
    const int* __restrict__ edst, const float* __restrict__ eval_,
    float* __restrict__ hi, int E)
{
    long long t = (long long)blockIdx.x * blockDim.x + threadIdx.x;
    int e = (int)(t >> 6);
    if (e >= E) return;
    int lane = (int)(t & 63);
    int s = esrc[e]; int d = edst[e]; float v = eval_[e];
    const float2 x = *reinterpret_cast<const float2*>(&input[(size_t)s * DFEAT + lane * 2]);
    float* p = &hi[(size_t)d * DFEAT + lane * 2];
    unsafeAtomicAdd(p,     x.x * v);
    unsafeAtomicAdd(p + 1, x.y * v);
}

template <bool BLEND>
__global__ __launch_bounds__(256) void gcn_epilogue(
    float* __restrict__ out, const float* __restrict__ h0,
    const float* __restrict__ inp, const float* __restrict__ W,
    const float* __restrict__ alpha, int N)
{
    __shared__ __hip_bfloat16 Wl[DFEAT * DFEAT];
    __shared__ float4 S4[16][DFEAT / 4];

    const float a   = 0.5f / (1.0f + __expf(-alpha[0]));
    const float oma = 1.0f - a;

    for (int i = threadIdx.x; i < DFEAT * DFEAT; i += 256) {
        int k = i >> 7, j = i & 127;
        float w = W[i] * THETA;
        if (k == j) w += 1.0f - THETA;
        Wl[i] = __float2bfloat16(w);
    }

    const int j  = threadIdx.x & 127;
    const int rg = threadIdx.x >> 7;

    for (int base = blockIdx.x * 16; base < N; base += gridDim.x * 16) {
        const int rows = min(16, N - base);
        __syncthreads();
        for (int i = threadIdx.x; i < rows * 32; i += 256) {
            int r = i >> 5, c = i & 31;
            size_t gph = (size_t)(base + r) * (DFEAT / 4) + c;
            float4 hv = reinterpret_cast<const float4*>(out)[gph];
            float4 sv;
            if (BLEND) {
                float4 h0v = reinterpret_cast<const float4*>(h0)[gph];
                sv.x = oma * hv.x + a * h0v.x;
                sv.y = oma * hv.y + a * h0v.y;
                sv.z = oma * hv.z + a * h0v.z;
                sv.w = oma * hv.w + a * h0v.w;
            } else {
                sv = hv;
            }
            S4[r][c] = sv;
        }
        __syncthreads();

        float acc[8];
        #pragma unroll
        for (int r = 0; r < 8; r++) acc[r] = 0.0f;
        for (int k = 0; k < DFEAT; k += 4) {
            float w0 = __bfloat162float(Wl[(k + 0) * DFEAT + j]);
            float w1 = __bfloat162float(Wl[(k + 1) * DFEAT + j]);
            float w2 = __bfloat162float(Wl[(k + 2) * DFEAT + j]);
            float w3 = __bfloat162float(Wl[(k + 3) * DFEAT + j]);
            #pragma unroll
            for (int r = 0; r < 8; r++) {
                float4 s4 = S4[rg * 8 + r][k >> 2];
                acc[r] = fmaf(s4.x, w0, acc[r]);
                acc[r] = fmaf(s4.y, w1, acc[r]);
                acc[r] = fmaf(s4.z, w2, acc[r]);
                acc[r] = fmaf(s4.w, w3, acc[r]);
            }
        }
        #pragma unroll
        for (int r = 0; r < 8; r++) {
            int rr = rg * 8 + r;
            if (rr < rows) {
                size_t gph = (size_t)(base + rr) * DFEAT + j;
                out[gph] = acc[r] + inp[gph];
            }
        }
    }
}

extern "C" void kernel_launch(void* const* d_in, const int* in_sizes, int n_in,
                              void* d_out, int out_size, void* d_ws, size_t ws_size,
                              hipStream_t stream) {
    const float* input = (const float*)d_in[0];
    const int*   esrc  = (const int*)  d_in[1];
    const int*   edst  = (const int*)  d_in[2];
    const float* eval_ = (const float*)d_in[3];
    const float* h0    = (const float*)d_in[4];
    const float* W     = (const float*)d_in[5];
    const float* alpha = (const float*)d_in[6];

    const int N = in_sizes[0] / DFEAT;
    const int E = in_sizes[1];
    float* out = (float*)d_out;
    const int B = (N + 255) / 256;

    // ---- Plan A layout (bytes)
    size_t bA_in16   = 0;
    size_t bA_csr    = (bA_in16 + (size_t)N * DFEAT * 2 + 15) & ~(size_t)15;
    size_t bA_rowptr = bA_csr + (size_t)E * 8;
    size_t bA_bkt    = bA_rowptr + (size_t)(N + 1) * 4;
    size_t bA_wp     = (bA_bkt + 2080 * 4 + 15) & ~(size_t)15;
    size_t needA     = bA_wp + (size_t)DFEAT * DFEAT * 2;

    // ---- Plan B layout (ints)
    size_t o_rowptr = 0;
    size_t o_cnt    = o_rowptr + (size_t)(N + 1);
    size_t o_part   = o_cnt + (size_t)N;
    size_t o_csr    = (o_part + 1024 + 1) & ~(size_t)1;
    size_t needB    = o_csr * 4 + (size_t)E * 8;

    const int NBUCK = (N + 255) >> 8;

    if (ws_size >= needA && N <= 131072 && N >= 1600) {
        unsigned short* in16 = (unsigned short*)((char*)d_ws + bA_in16);
        int2* csr    = (int2*)((char*)d_ws + bA_csr);
        int*  rowptr = (int*) ((char*)d_ws + bA_rowptr);
        int*  bcnt   = (int*) ((char*)d_ws + bA_bkt);          // [512]
        int*  bbase  = bcnt + 512;                              // [513]
        int*  tail   = bbase + 513;                             // [512]
        unsigned short* wp = (unsigned short*)((char*)d_ws + bA_wp);

        int n8     = N * DFEAT / 8;
        int ntiles = (N + 15) / 16;
        int nEB    = (E + 4095) / 4096;
        int cvtB   = (n8 + 511) / 512;

        hipMemsetAsync(bcnt, 0, 512 * sizeof(int), stream);
        k_cvt_hist<<<dim3(cvtB + nEB),   dim3(512), 0, stream>>>(input, (uint4*)in16,
                                                                 n8, cvtB, edst, bcnt, E);
        k_bscan_wprep<<<dim3(5),         dim3(512), 0, stream>>>(bcnt, bbase, tail,
                                                                 rowptr, NBUCK, N, E,
                                                                 W, wp);
        k_bpart<<<dim3(nEB),             dim3(512), 0, stream>>>(esrc, edst, eval_,
                                                                 tail, csr, E);
        k_bsort<<<dim3(NBUCK),           dim3(512), 0, stream>>>(bbase, csr, rowptr, N);
        k_fused4<<<dim3(ntiles),         dim3(256), 0, stream>>>(in16, csr, rowptr,
                                                                 h0, input, wp, alpha,
                                                                 out, N);
    } else if (ws_size >= needB && B <= 1024) {
        int*  rowptr = (int*)d_ws + o_rowptr;
        int*  cnt    = (int*)d_ws + o_cnt;
        int*  part   = (int*)d_ws + o_part;
        int2* csr    = (int2*)((int*)d_ws + o_csr);
        int E4 = (E + 3) / 4;

        hipMemsetAsync(cnt, 0, (size_t)N * sizeof(int), stream);
        k_hist <<<dim3((E4 + 255) / 256), dim3(256), 0, stream>>>(edst, cnt, E);
        k_scanA<<<dim3(B),               dim3(256), 0, stream>>>(cnt, part, N);
        k_scanB<<<dim3(1),               dim3(1024), 0, stream>>>(part, rowptr, B, N);
        k_scanC<<<dim3(B),               dim3(256), 0, stream>>>(cnt, part, rowptr, N);
        k_slot <<<dim3((E4 + 255) / 256), dim3(256), 0, stream>>>(esrc, edst, eval_,
                                                                  rowptr, cnt, csr, E);
        k_gather<<<dim3((N + 3) / 4),    dim3(256), 0, stream>>>(input, csr, rowptr,
                                                                 h0, alpha, out, N);
        gcn_epilogue<false><<<dim3(2048), dim3(256), 0, stream>>>(out, h0, input, W,
                                                                  alpha, N);
    } else {
        hipMemsetAsync(out, 0, (size_t)N * DFEAT * sizeof(float), stream);
        long long threads = (long long)E * 64;
        unsigned  nblk    = (unsigned)((threads + 255) / 256);
        gcn_scatter<<<dim3(nblk), dim3(256), 0, stream>>>(input, esrc, edst, eval_, out, E);
        gcn_epilogue<true><<<dim3(2048), dim3(256), 0, stream>>>(out, h0, input, W,
                                                                 alpha, N);
    }
}